// Round 7
// baseline (46107.404 us; speedup 1.0000x reference)
//
#include <hip/hip_runtime.h>
#include <stdint.h>

#define BATCHES 32
#define NPT     100000
#define NSAMP   1024
#define GPB     8          // groups (blocks) per batch; grid = 32*8 = 256
#define TPB     1024       // 16 waves: 0..14 compute (960 thr), 15 = sync wave
#define NCW     15         // compute waves
#define CTH     (NCW*64)   // 960 compute threads
#define PPB     12500      // points per (batch, group)
#define PPT     14         // k<13 full (12480), k==13: ct<20
#define TAILT   20

typedef unsigned long long u64;
typedef unsigned int u32;

// Mailbox rec[r&1][batch][group][8 u64] (6 used) — tag2-versioned words.
// tag2(r) = ((r>>1)+1)&3 in bits [63:62]; memset-0 invalid for r=0,1.
//   w0 = tag2 | key[61:0]
//   w1 = tag2 | key[63:62]<<60 | x<<28 | y>>4
//   w2 = tag2 | (y&0xF)<<58   | z<<26 | idx<<9      (idx: 17 bits)
//   w3..w5: same layout, group's 2nd-best candidate.
#define WS_BYTES (2 * BATCHES * GPB * 8 * 8)   // 32 KB

__device__ __forceinline__ void red_ki(u64& key, u32& idx, int off) {
    u64 ok = __shfl_xor(key, off, 64);
    u32 oi = __shfl_xor(idx, off, 64);
    if (ok > key || (ok == key && oi < idx)) { key = ok; idx = oi; }
}

__device__ __forceinline__ void red_step(u64& key, u32& idx, float& x, float& y, float& z, int off) {
    u64   ok = __shfl_xor(key, off, 64);
    u32   oi = __shfl_xor(idx, off, 64);
    float ox = __shfl_xor(x, off, 64);
    float oy = __shfl_xor(y, off, 64);
    float oz = __shfl_xor(z, off, 64);
    if (ok > key || (ok == key && oi < idx)) { key = ok; idx = oi; x = ox; y = oy; z = oz; }
}

// Recover xyz of a point this thread owns, by global idx (static indices only).
#define FIND_XYZ(IDX, RX, RY, RZ) do {                                   \
    RX = 0.f; RY = 0.f; RZ = 0.f;                                        \
    _Pragma("unroll")                                                    \
    for (int kk = 0; kk < PPT; ++kk) {                                   \
        bool h = (u32)(base + kk * CTH + ct) == (IDX);                   \
        RX = h ? px[kk] : RX; RY = h ? py[kk] : RY; RZ = h ? pz[kk] : RZ;\
    }                                                                    \
} while (0)

// Exact f64 update (matches float64 numpy bitwise: _rn ops forbid FMA;
// sum order ((dx^2+dy^2)+dz^2); sequential fmin per centroid).
#define UPDATE_LOOP(TWO) do {                                            \
    _Pragma("unroll")                                                    \
    for (int k = 0; k < PPT; ++k) {                                      \
        if (k == PPT - 1 && ct >= TAILT) break;                          \
        double dx = __dsub_rn((double)px[k], c1xd);                      \
        double dy = __dsub_rn((double)py[k], c1yd);                      \
        double dz = __dsub_rn((double)pz[k], c1zd);                      \
        double q2 = __dadd_rn(__dadd_rn(__dmul_rn(dx, dx),               \
                    __dmul_rn(dy, dy)), __dmul_rn(dz, dz));              \
        double nd = fmin(d[k], q2);                                      \
        if (TWO) {                                                       \
            double ex = __dsub_rn((double)px[k], c2xd);                  \
            double ey = __dsub_rn((double)py[k], c2yd);                  \
            double ez = __dsub_rn((double)pz[k], c2zd);                  \
            double e2 = __dadd_rn(__dadd_rn(__dmul_rn(ex, ex),           \
                        __dmul_rn(ey, ey)), __dmul_rn(ez, ez));          \
            nd = fmin(nd, e2);                                           \
        }                                                                \
        d[k] = nd;                                                       \
        u32 kidx = (u32)(base + k * CTH + ct);                           \
        bool g1 = nd > bd1;                                              \
        bool g2 = nd > bd2;                                              \
        bd2 = g1 ? bd1 : (g2 ? nd : bd2);                                \
        bi2 = g1 ? bi1 : (g2 ? kidx : bi2);                              \
        bd1 = g1 ? nd : bd1;                                             \
        bi1 = g1 ? kidx : bi1;                                           \
    }                                                                    \
} while (0)

__global__ void
__attribute__((amdgpu_flat_work_group_size(TPB, TPB), amdgpu_waves_per_eu(4, 4)))
fps_kernel(const float* __restrict__ coord,
           const int* __restrict__ seed_raw,
           float* __restrict__ out,
           u64* __restrict__ rec)
{
    const int tid  = threadIdx.x;
    const int lane = tid & 63;
    const int wid  = tid >> 6;
    const int b    = (int)blockIdx.x & (BATCHES - 1);   // batch 0..31
    const int g    = (int)blockIdx.x >> 5;              // group 0..7
    const int base = g * PPB;

    // Winner broadcast: 4 tagged words per round parity.
    //   v0 = tag2 | x1<<30 | y1>>2
    //   v1 = tag2 | (y1&3)<<60 | z1<<28 | idx1<<11 | valid2
    //   v2 = tag2 | x2<<30 | y2>>2
    //   v3 = tag2 | (y2&3)<<60 | z2<<28 | idx2<<11
    __shared__ u64 winw[2][4];
    __shared__ u32 sbar[8];
    __shared__ u64   Lk1[2][NCW], Lk2[2][NCW];
    __shared__ u32   Li1[2][NCW], Li2[2][NCW];
    __shared__ float Lx1[2][NCW], Ly1[2][NCW], Lz1[2][NCW];
    __shared__ float Lx2[2][NCW], Ly2[2][NCW], Lz2[2][NCW];

    if (tid < 8) { sbar[tid] = 0; ((u64*)winw)[tid] = 0ull; }
    __syncthreads();   // only block-wide barrier (before wave-role split)

    float* cent_out = out;                       // (B, 1024) as float
    float* samp_out = out + BATCHES * NSAMP;     // (B, 1024, 3)

    if (wid == NCW) {
        // ------- SYNC WAVE: poll top-2 mailbox, pick c1, speculate c2 -------
        const bool mine = lane < 6 * GPB;   // 48 poll lanes (logical word = lane)
        int m = 1;                          // centroids emitted (seed done by compute)
        for (int r = 0; ; ++r) {
            const u64 t2 = (u64)(((r >> 1) + 1) & 3);
            u64* slot = rec + ((size_t)((r & 1) * BATCHES + b) * GPB) * 8;
            u64* wp   = slot + (mine ? ((lane / 6) * 8 + (lane % 6)) : 0);
            u64 w = 0;
            for (;;) {
                bool ok = true;
                if (mine) {
                    w = __hip_atomic_load(wp, __ATOMIC_RELAXED, __HIP_MEMORY_SCOPE_AGENT);
                    ok = (w >> 62) == t2;
                }
                if (__ballot(ok) == ~0ull) break;
                __builtin_amdgcn_s_sleep(1);
            }
            // Redistribute: lane t<16 gets candidate (g=t&7, c=t>>3).
            const int q0 = (lane & 7) * 6 + ((lane >> 3) & 1) * 3;
            u64 w0 = __shfl(w, q0, 64);
            u64 w1 = __shfl(w, q0 + 1, 64);
            u64 w2 = __shfl(w, q0 + 2, 64);
            u64 ok3 = 0ull; u32 oi3 = 0xFFFFFFFFu;
            float ox3 = 0.f, oy3 = 0.f, oz3 = 0.f; double val = -1.0;
            if (lane < 16) {
                ok3 = (w0 & 0x3FFFFFFFFFFFFFFFull) | (((w1 >> 60) & 3ull) << 62);
                u32 xbt = (u32)(w1 >> 28);
                u32 ybt = (u32)(((w1 & 0xFFFFFFFull) << 4) | ((w2 >> 58) & 0xFull));
                u32 zbt = (u32)(w2 >> 26);
                oi3 = (u32)((w2 >> 9) & 0x1FFFFu);
                ox3 = __uint_as_float(xbt); oy3 = __uint_as_float(ybt); oz3 = __uint_as_float(zbt);
                val = __longlong_as_double((long long)ok3);
            }
            // pass 1: global winner c1 (butterfly over lanes 0..15)
            u64 ak = ok3; u32 ai = oi3; float ax = ox3, ay = oy3, az = oz3;
            red_step(ak, ai, ax, ay, az, 8); red_step(ak, ai, ax, ay, az, 4);
            red_step(ak, ai, ax, ay, az, 2); red_step(ak, ai, ax, ay, az, 1);
            // speculation: d' = min(val, |cand - c1|^2), exact
            u64 ddk = 0ull;
            if (lane < 16) {
                double dx = __dsub_rn((double)ox3, (double)ax);
                double dy = __dsub_rn((double)oy3, (double)ay);
                double dz = __dsub_rn((double)oz3, (double)az);
                double dist = __dadd_rn(__dadd_rn(__dmul_rn(dx, dx),
                              __dmul_rn(dy, dy)), __dmul_rn(dz, dz));
                double dd = fmin(val, dist);
                ddk = (u64)__double_as_longlong(dd);
            }
            // bound: max over groups of 2nd-best value (lanes 8..15 hold c=1)
            double msv = (lane >= 8 && lane < 16) ? val : -1.0;
            msv = fmax(msv, __shfl_xor(msv, 8, 64));
            msv = fmax(msv, __shfl_xor(msv, 4, 64));
            msv = fmax(msv, __shfl_xor(msv, 2, 64));
            msv = fmax(msv, __shfl_xor(msv, 1, 64));
            // pass 2: speculated winner c2
            u64 sk = ddk; u32 si = oi3; float sx = ox3, sy = oy3, sz = oz3;
            red_step(sk, si, sx, sy, sz, 8); red_step(sk, si, sx, sy, sz, 4);
            red_step(sk, si, sx, sy, sz, 2); red_step(sk, si, sx, sy, sz, 1);
            int valid = 0;
            if (lane == 0) {
                double sdd = __longlong_as_double((long long)sk);
                valid = (sdd > msv && (m + 2 <= NSAMP)) ? 1 : 0;
            }
            valid = __shfl(valid, 0, 64);
            if (lane == 0) {
                u32 x1b = __float_as_uint(ax), y1b = __float_as_uint(ay), z1b = __float_as_uint(az);
                u32 x2b = __float_as_uint(sx), y2b = __float_as_uint(sy), z2b = __float_as_uint(sz);
                u64 v0 = (t2 << 62) | ((u64)x1b << 30) | (u64)(y1b >> 2);
                u64 v1 = (t2 << 62) | ((u64)(y1b & 3u) << 60) | ((u64)z1b << 28) | ((u64)ai << 11) | (u64)valid;
                u64 v2 = (t2 << 62) | ((u64)x2b << 30) | (u64)(y2b >> 2);
                u64 v3 = (t2 << 62) | ((u64)(y2b & 3u) << 60) | ((u64)z2b << 28) | ((u64)si << 11);
                __hip_atomic_store(&winw[r & 1][0], v0, __ATOMIC_RELAXED, __HIP_MEMORY_SCOPE_WORKGROUP);
                __hip_atomic_store(&winw[r & 1][1], v1, __ATOMIC_RELAXED, __HIP_MEMORY_SCOPE_WORKGROUP);
                __hip_atomic_store(&winw[r & 1][2], v2, __ATOMIC_RELAXED, __HIP_MEMORY_SCOPE_WORKGROUP);
                __hip_atomic_store(&winw[r & 1][3], v3, __ATOMIC_RELAXED, __HIP_MEMORY_SCOPE_WORKGROUP);
            }
            m += 1 + valid;
            if (m >= NSAMP) break;
        }
        return;
    }

    // ---------------- COMPUTE WAVES (0..14) --------------------------------
    const int ct = tid;   // 0..959
    const float* cb = coord + (size_t)b * (NPT * 3);

    // Seed index (robust to int32 / int64 farthest_init materialization).
    int odd = 0;
    #pragma unroll
    for (int i = 1; i < 32; i += 2) odd |= seed_raw[i];
    u32 scur = (u32)((odd == 0) ? seed_raw[2 * b] : seed_raw[b]);
    float scx = cb[(size_t)scur * 3 + 0];
    float scy = cb[(size_t)scur * 3 + 1];
    float scz = cb[(size_t)scur * 3 + 2];

    float  px[PPT], py[PPT], pz[PPT];
    double d[PPT];
    #pragma unroll
    for (int k = 0; k < PPT; ++k) {
        bool v = (k < PPT - 1) || (ct < TAILT);
        int gi = base + (v ? (k * CTH + ct) : 0);
        px[k] = v ? cb[(size_t)gi * 3 + 0] : 0.f;
        py[k] = v ? cb[(size_t)gi * 3 + 1] : 0.f;
        pz[k] = v ? cb[(size_t)gi * 3 + 2] : 0.f;
        d[k]  = v ? 1.0e10 : 0.0;
    }

    if (g == 0 && wid == 1 && lane == 0) {          // emit seed (index 0)
        cent_out[b * NSAMP + 0] = (float)scur;
        size_t so = (size_t)(b * NSAMP) * 3;
        samp_out[so + 0] = scx; samp_out[so + 1] = scy; samp_out[so + 2] = scz;
    }

    int m = 1;
    float p1x = scx, p1y = scy, p1z = scz;
    float p2x = 0.f, p2y = 0.f, p2z = 0.f;
    int pend2 = 0;

    for (int r = 0; ; ++r) {
        const double c1xd = (double)p1x, c1yd = (double)p1y, c1zd = (double)p1z;
        const double c2xd = (double)p2x, c2yd = (double)p2y, c2zd = (double)p2z;
        double bd1 = -1.0, bd2 = -1.0; u32 bi1 = 0, bi2 = 0;
        if (pend2) { UPDATE_LOOP(1); } else { UPDATE_LOOP(0); }

        // Wave top-2: pass1 butterfly, then 2nd = max(winner's b2, others' b1).
        u64 kk1 = (u64)__double_as_longlong(bd1);
        u64 wk = kk1; u32 wi = bi1;
        red_ki(wk, wi, 32); red_ki(wk, wi, 16); red_ki(wk, wi, 8);
        red_ki(wk, wi, 4);  red_ki(wk, wi, 2);  red_ki(wk, wi, 1);
        bool iswin = (wi == bi1);
        u64 ck = iswin ? (u64)__double_as_longlong(bd2) : kk1;
        u32 ci = iswin ? bi2 : bi1;
        u64 wk2 = ck; u32 wi2 = ci;
        red_ki(wk2, wi2, 32); red_ki(wk2, wi2, 16); red_ki(wk2, wi2, 8);
        red_ki(wk2, wi2, 4);  red_ki(wk2, wi2, 2);  red_ki(wk2, wi2, 1);
        const int pb = r & 1;
        if (iswin) {                        // unique: deposits wave top1
            float fx, fy, fz; FIND_XYZ(bi1, fx, fy, fz);
            Lk1[pb][wid] = wk; Li1[pb][wid] = wi;
            Lx1[pb][wid] = fx; Ly1[pb][wid] = fy; Lz1[pb][wid] = fz;
        }
        if (ci == wi2) {                    // unique: deposits wave top2
            float fx, fy, fz; FIND_XYZ(ci, fx, fy, fz);
            Lk2[pb][wid] = wk2; Li2[pb][wid] = wi2;
            Lx2[pb][wid] = fx; Ly2[pb][wid] = fy; Lz2[pb][wid] = fz;
        }

        // Soft barrier over 15 compute waves (rolling counters).
        if (lane == 0)
            __hip_atomic_fetch_add(&sbar[r & 7], 1u, __ATOMIC_RELEASE, __HIP_MEMORY_SCOPE_WORKGROUP);
        const u32 tgt = (u32)(NCW * ((r >> 3) + 1));
        while (__hip_atomic_load(&sbar[r & 7], __ATOMIC_ACQUIRE, __HIP_MEMORY_SCOPE_WORKGROUP) < tgt) {}

        if (wid == 0) {
            // Merge 30 entries (15 wave-top1 on lanes 0..14, 15 wave-top2 on 16..30).
            u64 ek; u32 ei; float ex, ey, ez;
            if (lane < NCW) {
                ek = Lk1[pb][lane]; ei = Li1[pb][lane];
                ex = Lx1[pb][lane]; ey = Ly1[pb][lane]; ez = Lz1[pb][lane];
            } else if (lane >= 16 && lane < 16 + NCW) {
                int l = lane - 16;
                ek = Lk2[pb][l]; ei = Li2[pb][l];
                ex = Lx2[pb][l]; ey = Ly2[pb][l]; ez = Lz2[pb][l];
            } else { ek = 0ull; ei = 0xFFFFFFFFu; ex = ey = ez = 0.f; }
            u64 gk = ek; u32 gi1 = ei; float gx = ex, gy = ey, gz = ez;
            red_step(gk, gi1, gx, gy, gz, 32); red_step(gk, gi1, gx, gy, gz, 16);
            red_step(gk, gi1, gx, gy, gz, 8);  red_step(gk, gi1, gx, gy, gz, 4);
            red_step(gk, gi1, gx, gy, gz, 2);  red_step(gk, gi1, gx, gy, gz, 1);
            u64 hk = (ei == gi1) ? 0ull : ek;          // kill group-top1, re-reduce
            u32 hi = (ei == gi1) ? 0xFFFFFFFFu : ei;
            float hx = ex, hy = ey, hz = ez;
            red_step(hk, hi, hx, hy, hz, 32); red_step(hk, hi, hx, hy, hz, 16);
            red_step(hk, hi, hx, hy, hz, 8);  red_step(hk, hi, hx, hy, hz, 4);
            red_step(hk, hi, hx, hy, hz, 2);  red_step(hk, hi, hx, hy, hz, 1);
            if (lane == 0) {
                const u64 t2p = (u64)(((r >> 1) + 1) & 3);
                u64* rr = rec + ((size_t)((r & 1) * BATCHES + b) * GPB + g) * 8;
                u32 xb1 = __float_as_uint(gx), yb1 = __float_as_uint(gy), zb1 = __float_as_uint(gz);
                u32 xb2 = __float_as_uint(hx), yb2 = __float_as_uint(hy), zb2 = __float_as_uint(hz);
                u64 a0 = (t2p << 62) | (gk & 0x3FFFFFFFFFFFFFFFull);
                u64 a1 = (t2p << 62) | ((gk >> 62) << 60) | ((u64)xb1 << 28) | (u64)(yb1 >> 4);
                u64 a2 = (t2p << 62) | ((u64)(yb1 & 0xFu) << 58) | ((u64)zb1 << 26) | ((u64)gi1 << 9);
                u64 a3 = (t2p << 62) | (hk & 0x3FFFFFFFFFFFFFFFull);
                u64 a4 = (t2p << 62) | ((hk >> 62) << 60) | ((u64)xb2 << 28) | (u64)(yb2 >> 4);
                u64 a5 = (t2p << 62) | ((u64)(yb2 & 0xFu) << 58) | ((u64)zb2 << 26) | ((u64)hi << 9);
                __hip_atomic_store(&rr[0], a0, __ATOMIC_RELAXED, __HIP_MEMORY_SCOPE_AGENT);
                __hip_atomic_store(&rr[1], a1, __ATOMIC_RELAXED, __HIP_MEMORY_SCOPE_AGENT);
                __hip_atomic_store(&rr[2], a2, __ATOMIC_RELAXED, __HIP_MEMORY_SCOPE_AGENT);
                __hip_atomic_store(&rr[3], a3, __ATOMIC_RELAXED, __HIP_MEMORY_SCOPE_AGENT);
                __hip_atomic_store(&rr[4], a4, __ATOMIC_RELAXED, __HIP_MEMORY_SCOPE_AGENT);
                __hip_atomic_store(&rr[5], a5, __ATOMIC_RELAXED, __HIP_MEMORY_SCOPE_AGENT);
            }
        }

        // Spin for this round's delivery.
        const u64 t2 = (u64)(((r >> 1) + 1) & 3);
        u64 v0, v1, v2, v3;
        for (;;) {
            v0 = __hip_atomic_load(&winw[r & 1][0], __ATOMIC_RELAXED, __HIP_MEMORY_SCOPE_WORKGROUP);
            v1 = __hip_atomic_load(&winw[r & 1][1], __ATOMIC_RELAXED, __HIP_MEMORY_SCOPE_WORKGROUP);
            v2 = __hip_atomic_load(&winw[r & 1][2], __ATOMIC_RELAXED, __HIP_MEMORY_SCOPE_WORKGROUP);
            v3 = __hip_atomic_load(&winw[r & 1][3], __ATOMIC_RELAXED, __HIP_MEMORY_SCOPE_WORKGROUP);
            if (((v0 >> 62) == t2) & ((v1 >> 62) == t2) &
                ((v2 >> 62) == t2) & ((v3 >> 62) == t2)) break;
        }
        u32 x1b = (u32)(v0 >> 30);
        u32 y1b = (u32)(((v0 & 0x3FFFFFFFull) << 2) | ((v1 >> 60) & 3ull));
        u32 z1b = (u32)(v1 >> 28);
        u32 ni1 = (u32)((v1 >> 11) & 0x1FFFFu);
        int vbit = (int)(v1 & 1ull);
        u32 x2b = (u32)(v2 >> 30);
        u32 y2b = (u32)(((v2 & 0x3FFFFFFFull) << 2) | ((v3 >> 60) & 3ull));
        u32 z2b = (u32)(v3 >> 28);
        u32 ni2 = (u32)((v3 >> 11) & 0x1FFFFu);
        float nx1 = __uint_as_float(x1b), ny1 = __uint_as_float(y1b), nz1 = __uint_as_float(z1b);
        float nx2 = __uint_as_float(x2b), ny2 = __uint_as_float(y2b), nz2 = __uint_as_float(z2b);

        if (g == 0 && wid == 1 && lane == 0) {
            cent_out[b * NSAMP + m] = (float)ni1;
            size_t so = ((size_t)b * NSAMP + m) * 3;
            samp_out[so + 0] = nx1; samp_out[so + 1] = ny1; samp_out[so + 2] = nz1;
            if (vbit) {
                cent_out[b * NSAMP + m + 1] = (float)ni2;
                size_t so2 = ((size_t)b * NSAMP + m + 1) * 3;
                samp_out[so2 + 0] = nx2; samp_out[so2 + 1] = ny2; samp_out[so2 + 2] = nz2;
            }
        }
        m += 1 + vbit;
        if (m >= NSAMP) break;
        p1x = nx1; p1y = ny1; p1z = nz1;
        pend2 = vbit;
        p2x = nx2; p2y = ny2; p2z = nz2;
    }
}

extern "C" void kernel_launch(void* const* d_in, const int* in_sizes, int n_in,
                              void* d_out, int out_size, void* d_ws, size_t ws_size,
                              hipStream_t stream)
{
    const float* coord = (const float*)d_in[0];
    const int*   seed  = (const int*)d_in[1];
    float* out = (float*)d_out;
    u64* rec = (u64*)d_ws;

    hipMemsetAsync(d_ws, 0, WS_BYTES, stream);
    fps_kernel<<<dim3(BATCHES * GPB), dim3(TPB), 0, stream>>>(coord, seed, out, rec);
}

// Round 8
// 18962.164 us; speedup vs baseline: 2.4315x; 2.4315x over previous
//
#include <hip/hip_runtime.h>
#include <stdint.h>

#define BATCHES 32
#define NPT     100000
#define NSAMP   1024
#define GPB     16         // groups (blocks) per batch; grid = 32*16 = 512, 2 blocks/CU
#define TPB     1024       // 16 waves: 0..14 compute (960 thr), 15 = sync wave
#define NCW     15         // compute waves
#define CTH     (NCW*64)   // 960 compute threads
#define PPB     6250       // points per (batch, group)
#define PPT     7          // k<6 full (5760), k==6: ct<490
#define TAILT   490

typedef unsigned long long u64;
typedef unsigned int u32;

// Mailbox rec[r&1][batch][group][8 u64] (6 used) — tag2-versioned words.
// tag2(r) = ((r>>1)+1)&3 in bits [63:62]; memset-0 invalid for r=0,1.
//   w0 = tag2 | key[61:0]
//   w1 = tag2 | key[63:62]<<60 | x<<28 | y>>4
//   w2 = tag2 | (y&0xF)<<58   | z<<26 | idx<<9      (idx: 17 bits)
//   w3..w5: same layout, group's 2nd-best candidate.
#define WS_BYTES (2 * BATCHES * GPB * 8 * 8)   // 64 KB

__device__ __forceinline__ void red_ki(u64& key, u32& idx, int off) {
    u64 ok = __shfl_xor(key, off, 64);
    u32 oi = __shfl_xor(idx, off, 64);
    if (ok > key || (ok == key && oi < idx)) { key = ok; idx = oi; }
}

__device__ __forceinline__ void red_step(u64& key, u32& idx, float& x, float& y, float& z, int off) {
    u64   ok = __shfl_xor(key, off, 64);
    u32   oi = __shfl_xor(idx, off, 64);
    float ox = __shfl_xor(x, off, 64);
    float oy = __shfl_xor(y, off, 64);
    float oz = __shfl_xor(z, off, 64);
    if (ok > key || (ok == key && oi < idx)) { key = ok; idx = oi; x = ox; y = oy; z = oz; }
}

// Recover xyz of a point this thread owns, by global idx (static indices only).
#define FIND_XYZ(IDX, RX, RY, RZ) do {                                   \
    RX = 0.f; RY = 0.f; RZ = 0.f;                                        \
    _Pragma("unroll")                                                    \
    for (int kk = 0; kk < PPT; ++kk) {                                   \
        bool h = (u32)(base + kk * CTH + ct) == (IDX);                   \
        RX = h ? px[kk] : RX; RY = h ? py[kk] : RY; RZ = h ? pz[kk] : RZ;\
    }                                                                    \
} while (0)

__global__ void
__attribute__((amdgpu_flat_work_group_size(TPB, TPB), amdgpu_waves_per_eu(8, 8)))
fps_kernel(const float* __restrict__ coord,
           const int* __restrict__ seed_raw,
           float* __restrict__ out,
           u64* __restrict__ rec)
{
    const int tid  = threadIdx.x;
    const int lane = tid & 63;
    const int wid  = tid >> 6;
    const int b    = (int)blockIdx.x & (BATCHES - 1);   // batch 0..31
    const int g    = (int)blockIdx.x >> 5;              // group 0..15
    const int base = g * PPB;

    // Winner broadcast: 4 tagged words per round parity.
    //   v0 = tag2 | x1<<30 | y1>>2
    //   v1 = tag2 | (y1&3)<<60 | z1<<28 | idx1<<11 | valid2
    //   v2 = tag2 | x2<<30 | y2>>2
    //   v3 = tag2 | (y2&3)<<60 | z2<<28 | idx2<<11
    __shared__ u64 winw[2][4];
    __shared__ u32 sbar[8];
    __shared__ u64   Lk1[2][NCW], Lk2[2][NCW];
    __shared__ u32   Li1[2][NCW], Li2[2][NCW];
    __shared__ float Lx1[2][NCW], Ly1[2][NCW], Lz1[2][NCW];
    __shared__ float Lx2[2][NCW], Ly2[2][NCW], Lz2[2][NCW];

    if (tid < 8) { sbar[tid] = 0; ((u64*)winw)[tid] = 0ull; }
    __syncthreads();   // only block-wide barrier (before wave-role split)

    float* cent_out = out;                       // (B, 1024) as float
    float* samp_out = out + BATCHES * NSAMP;     // (B, 1024, 3)

    if (wid == NCW) {
        // ------- SYNC WAVE: poll top-2 mailbox, pick c1, speculate c2 -------
        const bool mine = lane < 3 * GPB;   // 48 poll lanes, 2 logical words each
        // logical word w in 0..95: group w/6, slot w%6, addr (w/6)*8 + w%6
        const int wlo = 2 * lane, whi = 2 * lane + 1;
        const int alo = mine ? ((wlo / 6) * 8 + (wlo % 6)) : 0;
        const int ahi = mine ? ((whi / 6) * 8 + (whi % 6)) : 0;
        int m = 1;                          // centroids emitted (seed by compute)
        for (int r = 0; ; ++r) {
            const u64 t2 = (u64)(((r >> 1) + 1) & 3);
            u64* slot = rec + ((size_t)((r & 1) * BATCHES + b) * GPB) * 8;
            u64 vlo = 0, vhi = 0;
            for (;;) {
                bool ok = true;
                if (mine) {
                    vlo = __hip_atomic_load(slot + alo, __ATOMIC_RELAXED, __HIP_MEMORY_SCOPE_AGENT);
                    vhi = __hip_atomic_load(slot + ahi, __ATOMIC_RELAXED, __HIP_MEMORY_SCOPE_AGENT);
                    ok = ((vlo >> 62) == t2) & ((vhi >> 62) == t2);
                }
                if (__ballot(ok) == ~0ull) break;
                __builtin_amdgcn_s_sleep(1);
            }
            // Redistribute: candidate lane cl<32 gets (group = cl&15, c = cl>>4).
            const int gg = lane & 15, cc = (lane >> 4) & 1;
            const int W0 = 6 * gg + 3 * cc;
            u64 s0lo = __shfl(vlo, W0 >> 1, 64),       s0hi = __shfl(vhi, W0 >> 1, 64);
            u64 s1lo = __shfl(vlo, (W0 + 1) >> 1, 64), s1hi = __shfl(vhi, (W0 + 1) >> 1, 64);
            u64 s2lo = __shfl(vlo, (W0 + 2) >> 1, 64), s2hi = __shfl(vhi, (W0 + 2) >> 1, 64);
            u64 w0 = (W0 & 1) ? s0hi : s0lo;
            u64 w1 = ((W0 + 1) & 1) ? s1hi : s1lo;
            u64 w2 = ((W0 + 2) & 1) ? s2hi : s2lo;
            u64 key = 0ull; u32 idx = 0xFFFFFFFFu;
            float ox3 = 0.f, oy3 = 0.f, oz3 = 0.f; double val = -1.0;
            if (lane < 32) {
                key = (w0 & 0x3FFFFFFFFFFFFFFFull) | (((w1 >> 60) & 3ull) << 62);
                u32 xbt = (u32)(w1 >> 28);
                u32 ybt = (u32)(((w1 & 0xFFFFFFFull) << 4) | ((w2 >> 58) & 0xFull));
                u32 zbt = (u32)(w2 >> 26);
                idx = (u32)((w2 >> 9) & 0x1FFFFu);
                ox3 = __uint_as_float(xbt); oy3 = __uint_as_float(ybt); oz3 = __uint_as_float(zbt);
                val = __longlong_as_double((long long)key);
            }
            // pass 1: global winner c1 (reduce over lanes 0..31)
            u64 ak = key; u32 ai = idx; float ax = ox3, ay = oy3, az = oz3;
            red_step(ak, ai, ax, ay, az, 16); red_step(ak, ai, ax, ay, az, 8);
            red_step(ak, ai, ax, ay, az, 4);  red_step(ak, ai, ax, ay, az, 2);
            red_step(ak, ai, ax, ay, az, 1);
            // speculation: d' = min(val, |cand - c1|^2), exact f64
            u64 ddk = 0ull;
            if (lane < 32) {
                double dx = __dsub_rn((double)ox3, (double)ax);
                double dy = __dsub_rn((double)oy3, (double)ay);
                double dz = __dsub_rn((double)oz3, (double)az);
                double dist = __dadd_rn(__dadd_rn(__dmul_rn(dx, dx),
                              __dmul_rn(dy, dy)), __dmul_rn(dz, dz));
                ddk = (u64)__double_as_longlong(fmin(val, dist));
            }
            // bound: max over groups of 2nd-best value (lanes 16..31 hold c=1)
            double msv = (lane >= 16 && lane < 32) ? val : -1.0;
            msv = fmax(msv, __shfl_xor(msv, 16, 64));
            msv = fmax(msv, __shfl_xor(msv, 8, 64));
            msv = fmax(msv, __shfl_xor(msv, 4, 64));
            msv = fmax(msv, __shfl_xor(msv, 2, 64));
            msv = fmax(msv, __shfl_xor(msv, 1, 64));
            // pass 2: speculated winner c2
            u64 sk = ddk; u32 si = idx; float sx = ox3, sy = oy3, sz = oz3;
            red_step(sk, si, sx, sy, sz, 16); red_step(sk, si, sx, sy, sz, 8);
            red_step(sk, si, sx, sy, sz, 4);  red_step(sk, si, sx, sy, sz, 2);
            red_step(sk, si, sx, sy, sz, 1);
            int valid = 0;
            if (lane == 0) {
                double sdd = __longlong_as_double((long long)sk);
                valid = (sdd > msv && (m + 2 <= NSAMP)) ? 1 : 0;
            }
            valid = __shfl(valid, 0, 64);
            if (lane == 0) {
                u32 x1b = __float_as_uint(ax), y1b = __float_as_uint(ay), z1b = __float_as_uint(az);
                u32 x2b = __float_as_uint(sx), y2b = __float_as_uint(sy), z2b = __float_as_uint(sz);
                u64 v0 = (t2 << 62) | ((u64)x1b << 30) | (u64)(y1b >> 2);
                u64 v1 = (t2 << 62) | ((u64)(y1b & 3u) << 60) | ((u64)z1b << 28) | ((u64)ai << 11) | (u64)valid;
                u64 v2 = (t2 << 62) | ((u64)x2b << 30) | (u64)(y2b >> 2);
                u64 v3 = (t2 << 62) | ((u64)(y2b & 3u) << 60) | ((u64)z2b << 28) | ((u64)si << 11);
                __hip_atomic_store(&winw[r & 1][0], v0, __ATOMIC_RELAXED, __HIP_MEMORY_SCOPE_WORKGROUP);
                __hip_atomic_store(&winw[r & 1][1], v1, __ATOMIC_RELAXED, __HIP_MEMORY_SCOPE_WORKGROUP);
                __hip_atomic_store(&winw[r & 1][2], v2, __ATOMIC_RELAXED, __HIP_MEMORY_SCOPE_WORKGROUP);
                __hip_atomic_store(&winw[r & 1][3], v3, __ATOMIC_RELAXED, __HIP_MEMORY_SCOPE_WORKGROUP);
            }
            m += 1 + valid;
            if (m >= NSAMP) break;
        }
        return;
    }

    // ---------------- COMPUTE WAVES (0..14) --------------------------------
    const int ct = tid;   // 0..959
    const float* cb = coord + (size_t)b * (NPT * 3);

    // Seed index (robust to int32 / int64 farthest_init materialization).
    int odd = 0;
    #pragma unroll
    for (int i = 1; i < 32; i += 2) odd |= seed_raw[i];
    u32 scur = (u32)((odd == 0) ? seed_raw[2 * b] : seed_raw[b]);
    float scx = cb[(size_t)scur * 3 + 0];
    float scy = cb[(size_t)scur * 3 + 1];
    float scz = cb[(size_t)scur * 3 + 2];

    // Coords (7 f32x3) + running f64 min-distance (7) in registers.
    float  px[PPT], py[PPT], pz[PPT];
    double d[PPT];
    #pragma unroll
    for (int k = 0; k < PPT; ++k) {
        bool v = (k < PPT - 1) || (ct < TAILT);
        int gi = base + (v ? (k * CTH + ct) : 0);
        px[k] = v ? cb[(size_t)gi * 3 + 0] : 0.f;
        py[k] = v ? cb[(size_t)gi * 3 + 1] : 0.f;
        pz[k] = v ? cb[(size_t)gi * 3 + 2] : 0.f;
        d[k]  = v ? 1.0e10 : 0.0;
    }

    if (g == 0 && wid == 1 && lane == 0) {          // emit seed (index 0)
        cent_out[b * NSAMP + 0] = (float)scur;
        size_t so = (size_t)(b * NSAMP) * 3;
        samp_out[so + 0] = scx; samp_out[so + 1] = scy; samp_out[so + 2] = scz;
    }

    int m = 1;
    float p1x = scx, p1y = scy, p1z = scz;
    float p2x = scx, p2y = scy, p2z = scz;   // c2==c1 => bitwise no-op round

    for (int r = 0; ; ++r) {
        // Exact f64 dual-centroid update + per-thread top-2 (matches float64
        // numpy bitwise: _rn ops forbid FMA; sum order ((dx^2+dy^2)+dz^2);
        // sequential fmin per centroid; fmin(fmin(d,q),q)==fmin(d,q)).
        const double c1xd = (double)p1x, c1yd = (double)p1y, c1zd = (double)p1z;
        const double c2xd = (double)p2x, c2yd = (double)p2y, c2zd = (double)p2z;
        double bd1 = -1.0, bd2 = -1.0; u32 bi1 = 0, bi2 = 0;
        #pragma unroll
        for (int k = 0; k < PPT; ++k) {
            if (k == PPT - 1 && ct >= TAILT) break;
            double dx = __dsub_rn((double)px[k], c1xd);
            double dy = __dsub_rn((double)py[k], c1yd);
            double dz = __dsub_rn((double)pz[k], c1zd);
            double q2 = __dadd_rn(__dadd_rn(__dmul_rn(dx, dx),
                        __dmul_rn(dy, dy)), __dmul_rn(dz, dz));
            double nd = fmin(d[k], q2);
            double ex = __dsub_rn((double)px[k], c2xd);
            double ey = __dsub_rn((double)py[k], c2yd);
            double ez = __dsub_rn((double)pz[k], c2zd);
            double e2 = __dadd_rn(__dadd_rn(__dmul_rn(ex, ex),
                        __dmul_rn(ey, ey)), __dmul_rn(ez, ez));
            nd = fmin(nd, e2);
            d[k] = nd;
            u32 kidx = (u32)(base + k * CTH + ct);
            bool g1 = nd > bd1;
            bool g2 = nd > bd2;
            bd2 = g1 ? bd1 : (g2 ? nd : bd2);
            bi2 = g1 ? bi1 : (g2 ? kidx : bi2);
            bd1 = g1 ? nd : bd1;
            bi1 = g1 ? kidx : bi1;
        }

        // Wave top-2: pass1 butterfly; pass2 with winner's entry demoted.
        u64 kk1 = (u64)__double_as_longlong(bd1);
        u64 wk = kk1; u32 wi = bi1;
        red_ki(wk, wi, 32); red_ki(wk, wi, 16); red_ki(wk, wi, 8);
        red_ki(wk, wi, 4);  red_ki(wk, wi, 2);  red_ki(wk, wi, 1);
        bool iswin = (wi == bi1);
        u64 ck = iswin ? (u64)__double_as_longlong(bd2) : kk1;
        u32 ci = iswin ? bi2 : bi1;
        u64 wk2 = ck; u32 wi2 = ci;
        red_ki(wk2, wi2, 32); red_ki(wk2, wi2, 16); red_ki(wk2, wi2, 8);
        red_ki(wk2, wi2, 4);  red_ki(wk2, wi2, 2);  red_ki(wk2, wi2, 1);
        const int pb = r & 1;
        if (iswin) {                        // unique lane: deposits wave top1
            float fx, fy, fz; FIND_XYZ(bi1, fx, fy, fz);
            Lk1[pb][wid] = wk; Li1[pb][wid] = wi;
            Lx1[pb][wid] = fx; Ly1[pb][wid] = fy; Lz1[pb][wid] = fz;
        }
        if (ci == wi2) {                    // unique lane: deposits wave top2
            float fx, fy, fz; FIND_XYZ(ci, fx, fy, fz);
            Lk2[pb][wid] = wk2; Li2[pb][wid] = wi2;
            Lx2[pb][wid] = fx; Ly2[pb][wid] = fy; Lz2[pb][wid] = fz;
        }

        // Soft barrier over 15 compute waves (rolling counters).
        if (lane == 0)
            __hip_atomic_fetch_add(&sbar[r & 7], 1u, __ATOMIC_RELEASE, __HIP_MEMORY_SCOPE_WORKGROUP);
        const u32 tgt = (u32)(NCW * ((r >> 3) + 1));
        while (__hip_atomic_load(&sbar[r & 7], __ATOMIC_ACQUIRE, __HIP_MEMORY_SCOPE_WORKGROUP) < tgt) {}

        if (wid == 0) {
            // Merge 30 entries (wave-top1 on lanes 0..14, wave-top2 on 16..30).
            u64 ek; u32 ei; float ex, ey, ez;
            if (lane < NCW) {
                ek = Lk1[pb][lane]; ei = Li1[pb][lane];
                ex = Lx1[pb][lane]; ey = Ly1[pb][lane]; ez = Lz1[pb][lane];
            } else if (lane >= 16 && lane < 16 + NCW) {
                int l = lane - 16;
                ek = Lk2[pb][l]; ei = Li2[pb][l];
                ex = Lx2[pb][l]; ey = Ly2[pb][l]; ez = Lz2[pb][l];
            } else { ek = 0ull; ei = 0xFFFFFFFFu; ex = ey = ez = 0.f; }
            u64 gk = ek; u32 gi1 = ei; float gx = ex, gy = ey, gz = ez;
            red_step(gk, gi1, gx, gy, gz, 32); red_step(gk, gi1, gx, gy, gz, 16);
            red_step(gk, gi1, gx, gy, gz, 8);  red_step(gk, gi1, gx, gy, gz, 4);
            red_step(gk, gi1, gx, gy, gz, 2);  red_step(gk, gi1, gx, gy, gz, 1);
            u64 hk = (ei == gi1) ? 0ull : ek;          // demote group-top1
            u32 hi = (ei == gi1) ? 0xFFFFFFFFu : ei;
            float hx = ex, hy = ey, hz = ez;
            red_step(hk, hi, hx, hy, hz, 32); red_step(hk, hi, hx, hy, hz, 16);
            red_step(hk, hi, hx, hy, hz, 8);  red_step(hk, hi, hx, hy, hz, 4);
            red_step(hk, hi, hx, hy, hz, 2);  red_step(hk, hi, hx, hy, hz, 1);
            if (lane == 0) {
                const u64 t2p = (u64)(((r >> 1) + 1) & 3);
                u64* rr = rec + ((size_t)((r & 1) * BATCHES + b) * GPB + g) * 8;
                u32 xb1 = __float_as_uint(gx), yb1 = __float_as_uint(gy), zb1 = __float_as_uint(gz);
                u32 xb2 = __float_as_uint(hx), yb2 = __float_as_uint(hy), zb2 = __float_as_uint(hz);
                u64 a0 = (t2p << 62) | (gk & 0x3FFFFFFFFFFFFFFFull);
                u64 a1 = (t2p << 62) | ((gk >> 62) << 60) | ((u64)xb1 << 28) | (u64)(yb1 >> 4);
                u64 a2 = (t2p << 62) | ((u64)(yb1 & 0xFu) << 58) | ((u64)zb1 << 26) | ((u64)gi1 << 9);
                u64 a3 = (t2p << 62) | (hk & 0x3FFFFFFFFFFFFFFFull);
                u64 a4 = (t2p << 62) | ((hk >> 62) << 60) | ((u64)xb2 << 28) | (u64)(yb2 >> 4);
                u64 a5 = (t2p << 62) | ((u64)(yb2 & 0xFu) << 58) | ((u64)zb2 << 26) | ((u64)hi << 9);
                __hip_atomic_store(&rr[0], a0, __ATOMIC_RELAXED, __HIP_MEMORY_SCOPE_AGENT);
                __hip_atomic_store(&rr[1], a1, __ATOMIC_RELAXED, __HIP_MEMORY_SCOPE_AGENT);
                __hip_atomic_store(&rr[2], a2, __ATOMIC_RELAXED, __HIP_MEMORY_SCOPE_AGENT);
                __hip_atomic_store(&rr[3], a3, __ATOMIC_RELAXED, __HIP_MEMORY_SCOPE_AGENT);
                __hip_atomic_store(&rr[4], a4, __ATOMIC_RELAXED, __HIP_MEMORY_SCOPE_AGENT);
                __hip_atomic_store(&rr[5], a5, __ATOMIC_RELAXED, __HIP_MEMORY_SCOPE_AGENT);
            }
        }

        // Spin for this round's delivery.
        const u64 t2 = (u64)(((r >> 1) + 1) & 3);
        u64 v0, v1, v2, v3;
        for (;;) {
            v0 = __hip_atomic_load(&winw[r & 1][0], __ATOMIC_RELAXED, __HIP_MEMORY_SCOPE_WORKGROUP);
            v1 = __hip_atomic_load(&winw[r & 1][1], __ATOMIC_RELAXED, __HIP_MEMORY_SCOPE_WORKGROUP);
            v2 = __hip_atomic_load(&winw[r & 1][2], __ATOMIC_RELAXED, __HIP_MEMORY_SCOPE_WORKGROUP);
            v3 = __hip_atomic_load(&winw[r & 1][3], __ATOMIC_RELAXED, __HIP_MEMORY_SCOPE_WORKGROUP);
            if (((v0 >> 62) == t2) & ((v1 >> 62) == t2) &
                ((v2 >> 62) == t2) & ((v3 >> 62) == t2)) break;
        }
        u32 x1b = (u32)(v0 >> 30);
        u32 y1b = (u32)(((v0 & 0x3FFFFFFFull) << 2) | ((v1 >> 60) & 3ull));
        u32 z1b = (u32)(v1 >> 28);
        u32 ni1 = (u32)((v1 >> 11) & 0x1FFFFu);
        int vbit = (int)(v1 & 1ull);
        u32 x2b = (u32)(v2 >> 30);
        u32 y2b = (u32)(((v2 & 0x3FFFFFFFull) << 2) | ((v3 >> 60) & 3ull));
        u32 z2b = (u32)(v3 >> 28);
        u32 ni2 = (u32)((v3 >> 11) & 0x1FFFFu);
        float nx1 = __uint_as_float(x1b), ny1 = __uint_as_float(y1b), nz1 = __uint_as_float(z1b);
        float nx2 = __uint_as_float(x2b), ny2 = __uint_as_float(y2b), nz2 = __uint_as_float(z2b);

        if (g == 0 && wid == 1 && lane == 0) {
            cent_out[b * NSAMP + m] = (float)ni1;
            size_t so = ((size_t)b * NSAMP + m) * 3;
            samp_out[so + 0] = nx1; samp_out[so + 1] = ny1; samp_out[so + 2] = nz1;
            if (vbit) {
                cent_out[b * NSAMP + m + 1] = (float)ni2;
                size_t so2 = ((size_t)b * NSAMP + m + 1) * 3;
                samp_out[so2 + 0] = nx2; samp_out[so2 + 1] = ny2; samp_out[so2 + 2] = nz2;
            }
        }
        m += 1 + vbit;
        if (m >= NSAMP) break;
        p1x = nx1; p1y = ny1; p1z = nz1;
        p2x = vbit ? nx2 : nx1;
        p2y = vbit ? ny2 : ny1;
        p2z = vbit ? nz2 : nz1;
    }
}

extern "C" void kernel_launch(void* const* d_in, const int* in_sizes, int n_in,
                              void* d_out, int out_size, void* d_ws, size_t ws_size,
                              hipStream_t stream)
{
    const float* coord = (const float*)d_in[0];
    const int*   seed  = (const int*)d_in[1];
    float* out = (float*)d_out;
    u64* rec = (u64*)d_ws;

    hipMemsetAsync(d_ws, 0, WS_BYTES, stream);
    fps_kernel<<<dim3(BATCHES * GPB), dim3(TPB), 0, stream>>>(coord, seed, out, rec);
}

// Round 9
// 6401.501 us; speedup vs baseline: 7.2026x; 2.9621x over previous
//
#include <hip/hip_runtime.h>
#include <stdint.h>

#define BATCHES 32
#define NPT     100000
#define NSAMP   1024
#define GPB     16         // groups (blocks) per batch
#define NPAIR   16         // batch pairs; block serves batches (p, p+16)
#define TPB     1024       // 16 waves: 0..14 compute (960 thr), 15 = sync wave
#define NCW     15         // compute waves
#define CTH     (NCW*64)   // 960 compute threads
#define PPB     6250       // points per (batch, group)
#define PPT     7          // k<6 full (5760), k==6: ct<490
#define TAILT   490

typedef unsigned long long u64;
typedef unsigned int u32;

// Mailbox rec[r&1][batch][group][8 u64] (6 used) — tag2-versioned words.
// tag2(r) = ((r>>1)+1)&3 in bits [63:62]; memset-0 invalid for r=0,1.
//   w0 = tag2 | key[61:0]
//   w1 = tag2 | key[63:62]<<60 | x<<28 | y>>4
//   w2 = tag2 | (y&0xF)<<58   | z<<26 | idx<<9      (idx: 17 bits)
//   w3..w5: same layout, group's 2nd-best candidate.
#define WS_BYTES (2 * BATCHES * GPB * 8 * 8)   // 64 KB

__device__ __forceinline__ void red_ki(u64& key, u32& idx, int off) {
    u64 ok = __shfl_xor(key, off, 64);
    u32 oi = __shfl_xor(idx, off, 64);
    if (ok > key || (ok == key && oi < idx)) { key = ok; idx = oi; }
}

__device__ __forceinline__ void red_step(u64& key, u32& idx, float& x, float& y, float& z, int off) {
    u64   ok = __shfl_xor(key, off, 64);
    u32   oi = __shfl_xor(idx, off, 64);
    float ox = __shfl_xor(x, off, 64);
    float oy = __shfl_xor(y, off, 64);
    float oz = __shfl_xor(z, off, 64);
    if (ok > key || (ok == key && oi < idx)) { key = ok; idx = oi; x = ox; y = oy; z = oz; }
}

// Recover xyz of a point this thread owns, by global idx (static indices only).
#define FIND_XYZ(XB, IDX, RX, RY, RZ) do {                                \
    RX = 0.f; RY = 0.f; RZ = 0.f;                                         \
    _Pragma("unroll")                                                     \
    for (int kk = 0; kk < PPT; ++kk) {                                    \
        bool h = (u32)(base + kk * CTH + ct) == (IDX);                    \
        RX = h ? px[XB][kk] : RX; RY = h ? py[XB][kk] : RY;               \
        RZ = h ? pz[XB][kk] : RZ;                                         \
    }                                                                     \
} while (0)

__global__ void
__attribute__((amdgpu_flat_work_group_size(TPB, TPB), amdgpu_waves_per_eu(4, 4)))
fps_kernel(const float* __restrict__ coord,
           const int* __restrict__ seed_raw,
           float* __restrict__ out,
           u64* __restrict__ rec)
{
    const int tid  = threadIdx.x;
    const int lane = tid & 63;
    const int wid  = tid >> 6;
    const int p    = (int)blockIdx.x & (NPAIR - 1);   // pair id
    const int g    = (int)blockIdx.x >> 4;            // group 0..15
    const int base = g * PPB;
    const int bA = p, bB = p + NPAIR;

    // Per-thread f64 running min-distance lives in LDS (register relief —
    // each thread touches only [..][ct]; lane stride 8 B = free 2-way alias).
    __shared__ double dlds[2][PPT][CTH];              // 107,520 B
    // Winner broadcast: 4 tagged words per (batch, round parity).
    //   v0 = tag2 | x1<<30 | y1>>2
    //   v1 = tag2 | (y1&3)<<60 | z1<<28 | idx1<<11 | valid2
    //   v2 = tag2 | x2<<30 | y2>>2
    //   v3 = tag2 | (y2&3)<<60 | z2<<28 | idx2<<11
    __shared__ u64 winw[2][2][4];    // [xb][r&1][word]
    __shared__ u32 sbar[2][4];       // [xb][r&3] rolling counters
    __shared__ u64   Lk1[2][NCW], Lk2[2][NCW];
    __shared__ u32   Li1[2][NCW], Li2[2][NCW];
    __shared__ float Lx1[2][NCW], Ly1[2][NCW], Lz1[2][NCW];
    __shared__ float Lx2[2][NCW], Ly2[2][NCW], Lz2[2][NCW];

    if (tid < 8)  ((u32*)sbar)[tid] = 0u;
    if (tid < 16) ((u64*)winw)[tid] = 0ull;
    __syncthreads();   // only block-wide barrier (before wave-role split)

    float* cent_out = out;                       // (B, 1024) as float
    float* samp_out = out + BATCHES * NSAMP;     // (B, 1024, 3)

    if (wid == NCW) {
        // ------- SYNC WAVE: per round, per batch: poll top-2 mailbox,
        //         pick c1 exactly, speculate c2 under the sound bound. ------
        const bool mine = lane < 3 * GPB;   // 48 poll lanes, 2 logical words each
        const int wlo = 2 * lane, whi = 2 * lane + 1;
        const int alo = mine ? ((wlo / 6) * 8 + (wlo % 6)) : 0;
        const int ahi = mine ? ((whi / 6) * 8 + (whi % 6)) : 0;
        int mm0 = 1, mm1 = 1;
        for (int r = 0;; ++r) {
            const u64 t2 = (u64)(((r >> 1) + 1) & 3);
            #pragma unroll
            for (int xb = 0; xb < 2; ++xb) {
                int mcur = xb ? mm1 : mm0;
                if (mcur >= NSAMP) continue;
                const int batch = xb ? bB : bA;
                u64* slot = rec + ((size_t)((r & 1) * BATCHES + batch) * GPB) * 8;
                u64 vlo = 0, vhi = 0;
                for (;;) {
                    bool ok = true;
                    if (mine) {
                        vlo = __hip_atomic_load(slot + alo, __ATOMIC_RELAXED, __HIP_MEMORY_SCOPE_AGENT);
                        vhi = __hip_atomic_load(slot + ahi, __ATOMIC_RELAXED, __HIP_MEMORY_SCOPE_AGENT);
                        ok = ((vlo >> 62) == t2) & ((vhi >> 62) == t2);
                    }
                    if (__ballot(ok) == ~0ull) break;
                    __builtin_amdgcn_s_sleep(1);
                }
                // Redistribute: candidate lane cl<32 gets (group=cl&15, c=cl>>4).
                const int gg = lane & 15, cc = (lane >> 4) & 1;
                const int W0 = 6 * gg + 3 * cc;
                u64 s0lo = __shfl(vlo, W0 >> 1, 64),       s0hi = __shfl(vhi, W0 >> 1, 64);
                u64 s1lo = __shfl(vlo, (W0 + 1) >> 1, 64), s1hi = __shfl(vhi, (W0 + 1) >> 1, 64);
                u64 s2lo = __shfl(vlo, (W0 + 2) >> 1, 64), s2hi = __shfl(vhi, (W0 + 2) >> 1, 64);
                u64 w0 = (W0 & 1) ? s0hi : s0lo;
                u64 w1 = ((W0 + 1) & 1) ? s1hi : s1lo;
                u64 w2 = ((W0 + 2) & 1) ? s2hi : s2lo;
                u64 key = 0ull; u32 idx = 0xFFFFFFFFu;
                float ox = 0.f, oy = 0.f, oz = 0.f; double val = -1.0;
                if (lane < 32) {
                    key = (w0 & 0x3FFFFFFFFFFFFFFFull) | (((w1 >> 60) & 3ull) << 62);
                    u32 xbt = (u32)(w1 >> 28);
                    u32 ybt = (u32)(((w1 & 0xFFFFFFFull) << 4) | ((w2 >> 58) & 0xFull));
                    u32 zbt = (u32)(w2 >> 26);
                    idx = (u32)((w2 >> 9) & 0x1FFFFu);
                    ox = __uint_as_float(xbt); oy = __uint_as_float(ybt); oz = __uint_as_float(zbt);
                    val = __longlong_as_double((long long)key);
                }
                // pass 1: global winner c1
                u64 ak = key; u32 ai = idx; float ax = ox, ay = oy, az = oz;
                red_step(ak, ai, ax, ay, az, 16); red_step(ak, ai, ax, ay, az, 8);
                red_step(ak, ai, ax, ay, az, 4);  red_step(ak, ai, ax, ay, az, 2);
                red_step(ak, ai, ax, ay, az, 1);
                // speculation: d' = min(val, |cand - c1|^2), exact f64
                u64 ddk = 0ull;
                if (lane < 32) {
                    double dx = __dsub_rn((double)ox, (double)ax);
                    double dy = __dsub_rn((double)oy, (double)ay);
                    double dz = __dsub_rn((double)oz, (double)az);
                    double dist = __dadd_rn(__dadd_rn(__dmul_rn(dx, dx),
                                  __dmul_rn(dy, dy)), __dmul_rn(dz, dz));
                    ddk = (u64)__double_as_longlong(fmin(val, dist));
                }
                // bound: max over groups of 2nd-best value (lanes 16..31)
                double msv = (lane >= 16 && lane < 32) ? val : -1.0;
                msv = fmax(msv, __shfl_xor(msv, 16, 64));
                msv = fmax(msv, __shfl_xor(msv, 8, 64));
                msv = fmax(msv, __shfl_xor(msv, 4, 64));
                msv = fmax(msv, __shfl_xor(msv, 2, 64));
                msv = fmax(msv, __shfl_xor(msv, 1, 64));
                // pass 2: speculated winner c2
                u64 sk = ddk; u32 si = idx; float qx = ox, qy = oy, qz = oz;
                red_step(sk, si, qx, qy, qz, 16); red_step(sk, si, qx, qy, qz, 8);
                red_step(sk, si, qx, qy, qz, 4);  red_step(sk, si, qx, qy, qz, 2);
                red_step(sk, si, qx, qy, qz, 1);
                int valid = 0;
                if (lane == 0) {
                    double sdd = __longlong_as_double((long long)sk);
                    valid = (sdd > msv && (mcur + 2 <= NSAMP)) ? 1 : 0;
                }
                valid = __shfl(valid, 0, 64);
                if (lane == 0) {
                    u32 x1b = __float_as_uint(ax), y1b = __float_as_uint(ay), z1b = __float_as_uint(az);
                    u32 x2b = __float_as_uint(qx), y2b = __float_as_uint(qy), z2b = __float_as_uint(qz);
                    u64 v0 = (t2 << 62) | ((u64)x1b << 30) | (u64)(y1b >> 2);
                    u64 v1 = (t2 << 62) | ((u64)(y1b & 3u) << 60) | ((u64)z1b << 28) | ((u64)ai << 11) | (u64)valid;
                    u64 v2 = (t2 << 62) | ((u64)x2b << 30) | (u64)(y2b >> 2);
                    u64 v3 = (t2 << 62) | ((u64)(y2b & 3u) << 60) | ((u64)z2b << 28) | ((u64)si << 11);
                    __hip_atomic_store(&winw[xb][r & 1][0], v0, __ATOMIC_RELAXED, __HIP_MEMORY_SCOPE_WORKGROUP);
                    __hip_atomic_store(&winw[xb][r & 1][1], v1, __ATOMIC_RELAXED, __HIP_MEMORY_SCOPE_WORKGROUP);
                    __hip_atomic_store(&winw[xb][r & 1][2], v2, __ATOMIC_RELAXED, __HIP_MEMORY_SCOPE_WORKGROUP);
                    __hip_atomic_store(&winw[xb][r & 1][3], v3, __ATOMIC_RELAXED, __HIP_MEMORY_SCOPE_WORKGROUP);
                }
                mcur += 1 + valid;
                if (xb) mm1 = mcur; else mm0 = mcur;
            }
            if (mm0 >= NSAMP && mm1 >= NSAMP) break;
        }
        return;
    }

    // ---------------- COMPUTE WAVES (0..14), two-batch interleave ----------
    const int ct = tid;   // 0..959

    // Seed indices (robust to int32 / int64 farthest_init materialization).
    int odd = 0;
    #pragma unroll
    for (int i = 1; i < 32; i += 2) odd |= seed_raw[i];
    u32 scur[2]; float ssx[2], ssy[2], ssz[2];
    #pragma unroll
    for (int xb = 0; xb < 2; ++xb) {
        const int batch = xb ? bB : bA;
        const float* cb = coord + (size_t)batch * (NPT * 3);
        scur[xb] = (u32)((odd == 0) ? seed_raw[2 * batch] : seed_raw[batch]);
        ssx[xb] = cb[(size_t)scur[xb] * 3 + 0];
        ssy[xb] = cb[(size_t)scur[xb] * 3 + 1];
        ssz[xb] = cb[(size_t)scur[xb] * 3 + 2];
    }

    // Coords (2x7 f32x3) in registers; d in LDS.
    float px[2][PPT], py[2][PPT], pz[2][PPT];
    #pragma unroll
    for (int xb = 0; xb < 2; ++xb) {
        const float* cb = coord + (size_t)((xb ? bB : bA)) * (NPT * 3);
        #pragma unroll
        for (int k = 0; k < PPT; ++k) {
            bool v = (k < PPT - 1) || (ct < TAILT);
            int gi = base + (v ? (k * CTH + ct) : 0);
            px[xb][k] = v ? cb[(size_t)gi * 3 + 0] : 0.f;
            py[xb][k] = v ? cb[(size_t)gi * 3 + 1] : 0.f;
            pz[xb][k] = v ? cb[(size_t)gi * 3 + 2] : 0.f;
            dlds[xb][k][ct] = v ? 1.0e10 : 0.0;
        }
    }

    if (g == 0 && wid == 1 && lane == 0) {      // emit seeds (index 0)
        #pragma unroll
        for (int xb = 0; xb < 2; ++xb) {
            const int batch = xb ? bB : bA;
            cent_out[batch * NSAMP + 0] = (float)scur[xb];
            size_t so = (size_t)(batch * NSAMP) * 3;
            samp_out[so + 0] = ssx[xb]; samp_out[so + 1] = ssy[xb]; samp_out[so + 2] = ssz[xb];
        }
    }

    int mm[2] = {1, 1};
    int done[2] = {0, 0};

    for (int r = 0;; ++r) {
        #pragma unroll
        for (int xb = 0; xb < 2; ++xb) {
            if (done[xb]) continue;
            const int batch = xb ? bB : bA;
            float c1x, c1y, c1z, c2x, c2y, c2z;
            if (r == 0) {
                c1x = ssx[xb]; c1y = ssy[xb]; c1z = ssz[xb];
                c2x = c1x; c2y = c1y; c2z = c1z;   // c2==c1 => bitwise no-op
            } else {
                const int rr = r - 1;
                const u64 t2 = (u64)(((rr >> 1) + 1) & 3);
                u64 v0, v1, v2, v3;
                for (;;) {   // LDS spin — sync wave delivers
                    v0 = __hip_atomic_load(&winw[xb][rr & 1][0], __ATOMIC_RELAXED, __HIP_MEMORY_SCOPE_WORKGROUP);
                    v1 = __hip_atomic_load(&winw[xb][rr & 1][1], __ATOMIC_RELAXED, __HIP_MEMORY_SCOPE_WORKGROUP);
                    v2 = __hip_atomic_load(&winw[xb][rr & 1][2], __ATOMIC_RELAXED, __HIP_MEMORY_SCOPE_WORKGROUP);
                    v3 = __hip_atomic_load(&winw[xb][rr & 1][3], __ATOMIC_RELAXED, __HIP_MEMORY_SCOPE_WORKGROUP);
                    if (((v0 >> 62) == t2) & ((v1 >> 62) == t2) &
                        ((v2 >> 62) == t2) & ((v3 >> 62) == t2)) break;
                }
                u32 x1b = (u32)(v0 >> 30);
                u32 y1b = (u32)(((v0 & 0x3FFFFFFFull) << 2) | ((v1 >> 60) & 3ull));
                u32 z1b = (u32)(v1 >> 28);
                u32 ni1 = (u32)((v1 >> 11) & 0x1FFFFu);
                int vbit = (int)(v1 & 1ull);
                u32 x2b = (u32)(v2 >> 30);
                u32 y2b = (u32)(((v2 & 0x3FFFFFFFull) << 2) | ((v3 >> 60) & 3ull));
                u32 z2b = (u32)(v3 >> 28);
                u32 ni2 = (u32)((v3 >> 11) & 0x1FFFFu);
                float nx1 = __uint_as_float(x1b), ny1 = __uint_as_float(y1b), nz1 = __uint_as_float(z1b);
                float nx2 = __uint_as_float(x2b), ny2 = __uint_as_float(y2b), nz2 = __uint_as_float(z2b);
                if (g == 0 && wid == 1 && lane == 0) {
                    cent_out[batch * NSAMP + mm[xb]] = (float)ni1;
                    size_t so = ((size_t)batch * NSAMP + mm[xb]) * 3;
                    samp_out[so + 0] = nx1; samp_out[so + 1] = ny1; samp_out[so + 2] = nz1;
                    if (vbit) {
                        cent_out[batch * NSAMP + mm[xb] + 1] = (float)ni2;
                        samp_out[so + 3] = nx2; samp_out[so + 4] = ny2; samp_out[so + 5] = nz2;
                    }
                }
                mm[xb] += 1 + vbit;
                if (mm[xb] >= NSAMP) { done[xb] = 1; continue; }
                c1x = nx1; c1y = ny1; c1z = nz1;
                c2x = vbit ? nx2 : nx1;
                c2y = vbit ? ny2 : ny1;
                c2z = vbit ? nz2 : nz1;
            }

            // Exact f64 dual-centroid update + per-thread top-2 (float64-numpy
            // bitwise: _rn forbids FMA; sum order ((dx^2+dy^2)+dz^2);
            // sequential fmin; fmin(fmin(d,q),q)==fmin(d,q)).
            const double c1xd = (double)c1x, c1yd = (double)c1y, c1zd = (double)c1z;
            const double c2xd = (double)c2x, c2yd = (double)c2y, c2zd = (double)c2z;
            double bd1 = -1.0, bd2 = -1.0; u32 bi1 = 0, bi2 = 0;
            #pragma unroll
            for (int k = 0; k < PPT; ++k) {
                if (k == PPT - 1 && ct >= TAILT) break;
                double dx = __dsub_rn((double)px[xb][k], c1xd);
                double dy = __dsub_rn((double)py[xb][k], c1yd);
                double dz = __dsub_rn((double)pz[xb][k], c1zd);
                double q2 = __dadd_rn(__dadd_rn(__dmul_rn(dx, dx),
                            __dmul_rn(dy, dy)), __dmul_rn(dz, dz));
                double nd = fmin(dlds[xb][k][ct], q2);
                double ex = __dsub_rn((double)px[xb][k], c2xd);
                double ey = __dsub_rn((double)py[xb][k], c2yd);
                double ez = __dsub_rn((double)pz[xb][k], c2zd);
                double e2 = __dadd_rn(__dadd_rn(__dmul_rn(ex, ex),
                            __dmul_rn(ey, ey)), __dmul_rn(ez, ez));
                nd = fmin(nd, e2);
                dlds[xb][k][ct] = nd;
                u32 kidx = (u32)(base + k * CTH + ct);
                bool g1 = nd > bd1;
                bool g2 = nd > bd2;
                bd2 = g1 ? bd1 : (g2 ? nd : bd2);
                bi2 = g1 ? bi1 : (g2 ? kidx : bi2);
                bd1 = g1 ? nd : bd1;
                bi1 = g1 ? kidx : bi1;
            }

            // Wave top-2: pass1 butterfly; pass2 with winner's entry demoted.
            u64 kk1 = (u64)__double_as_longlong(bd1);
            u64 wk = kk1; u32 wi = bi1;
            red_ki(wk, wi, 32); red_ki(wk, wi, 16); red_ki(wk, wi, 8);
            red_ki(wk, wi, 4);  red_ki(wk, wi, 2);  red_ki(wk, wi, 1);
            bool iswin = (wi == bi1);
            u64 ck = iswin ? (u64)__double_as_longlong(bd2) : kk1;
            u32 ci = iswin ? bi2 : bi1;
            u64 wk2 = ck; u32 wi2 = ci;
            red_ki(wk2, wi2, 32); red_ki(wk2, wi2, 16); red_ki(wk2, wi2, 8);
            red_ki(wk2, wi2, 4);  red_ki(wk2, wi2, 2);  red_ki(wk2, wi2, 1);
            if (iswin) {                        // unique lane: wave top1
                float fx, fy, fz; FIND_XYZ(xb, bi1, fx, fy, fz);
                Lk1[xb][wid] = wk; Li1[xb][wid] = wi;
                Lx1[xb][wid] = fx; Ly1[xb][wid] = fy; Lz1[xb][wid] = fz;
            }
            if (ci == wi2) {                    // unique lane: wave top2
                float fx, fy, fz; FIND_XYZ(xb, ci, fx, fy, fz);
                Lk2[xb][wid] = wk2; Li2[xb][wid] = wi2;
                Lx2[xb][wid] = fx; Ly2[xb][wid] = fy; Lz2[xb][wid] = fz;
            }

            // Per-batch soft barrier; only the leader wave (wid==xb) waits.
            if (lane == 0)
                __hip_atomic_fetch_add(&sbar[xb][r & 3], 1u, __ATOMIC_RELEASE, __HIP_MEMORY_SCOPE_WORKGROUP);

            if (wid == xb) {
                const u32 tgt = (u32)(NCW * ((r >> 2) + 1));
                while (__hip_atomic_load(&sbar[xb][r & 3], __ATOMIC_ACQUIRE, __HIP_MEMORY_SCOPE_WORKGROUP) < tgt) {}
                // Merge 30 entries (wave-top1 lanes 0..14, wave-top2 16..30).
                u64 ek; u32 ei; float ex, ey, ez;
                if (lane < NCW) {
                    ek = Lk1[xb][lane]; ei = Li1[xb][lane];
                    ex = Lx1[xb][lane]; ey = Ly1[xb][lane]; ez = Lz1[xb][lane];
                } else if (lane >= 16 && lane < 16 + NCW) {
                    int l = lane - 16;
                    ek = Lk2[xb][l]; ei = Li2[xb][l];
                    ex = Lx2[xb][l]; ey = Ly2[xb][l]; ez = Lz2[xb][l];
                } else { ek = 0ull; ei = 0xFFFFFFFFu; ex = ey = ez = 0.f; }
                u64 gk = ek; u32 gi1 = ei; float gx = ex, gy = ey, gz = ez;
                red_step(gk, gi1, gx, gy, gz, 32); red_step(gk, gi1, gx, gy, gz, 16);
                red_step(gk, gi1, gx, gy, gz, 8);  red_step(gk, gi1, gx, gy, gz, 4);
                red_step(gk, gi1, gx, gy, gz, 2);  red_step(gk, gi1, gx, gy, gz, 1);
                u64 hk = (ei == gi1) ? 0ull : ek;          // demote group-top1
                u32 hi = (ei == gi1) ? 0xFFFFFFFFu : ei;
                float hx = ex, hy = ey, hz = ez;
                red_step(hk, hi, hx, hy, hz, 32); red_step(hk, hi, hx, hy, hz, 16);
                red_step(hk, hi, hx, hy, hz, 8);  red_step(hk, hi, hx, hy, hz, 4);
                red_step(hk, hi, hx, hy, hz, 2);  red_step(hk, hi, hx, hy, hz, 1);
                if (lane == 0) {
                    const u64 t2p = (u64)(((r >> 1) + 1) & 3);
                    u64* rr2 = rec + ((size_t)((r & 1) * BATCHES + batch) * GPB + g) * 8;
                    u32 xb1 = __float_as_uint(gx), yb1 = __float_as_uint(gy), zb1 = __float_as_uint(gz);
                    u32 xb2 = __float_as_uint(hx), yb2 = __float_as_uint(hy), zb2 = __float_as_uint(hz);
                    u64 a0 = (t2p << 62) | (gk & 0x3FFFFFFFFFFFFFFFull);
                    u64 a1 = (t2p << 62) | ((gk >> 62) << 60) | ((u64)xb1 << 28) | (u64)(yb1 >> 4);
                    u64 a2 = (t2p << 62) | ((u64)(yb1 & 0xFu) << 58) | ((u64)zb1 << 26) | ((u64)gi1 << 9);
                    u64 a3 = (t2p << 62) | (hk & 0x3FFFFFFFFFFFFFFFull);
                    u64 a4 = (t2p << 62) | ((hk >> 62) << 60) | ((u64)xb2 << 28) | (u64)(yb2 >> 4);
                    u64 a5 = (t2p << 62) | ((u64)(yb2 & 0xFu) << 58) | ((u64)zb2 << 26) | ((u64)hi << 9);
                    __hip_atomic_store(&rr2[0], a0, __ATOMIC_RELAXED, __HIP_MEMORY_SCOPE_AGENT);
                    __hip_atomic_store(&rr2[1], a1, __ATOMIC_RELAXED, __HIP_MEMORY_SCOPE_AGENT);
                    __hip_atomic_store(&rr2[2], a2, __ATOMIC_RELAXED, __HIP_MEMORY_SCOPE_AGENT);
                    __hip_atomic_store(&rr2[3], a3, __ATOMIC_RELAXED, __HIP_MEMORY_SCOPE_AGENT);
                    __hip_atomic_store(&rr2[4], a4, __ATOMIC_RELAXED, __HIP_MEMORY_SCOPE_AGENT);
                    __hip_atomic_store(&rr2[5], a5, __ATOMIC_RELAXED, __HIP_MEMORY_SCOPE_AGENT);
                }
            }
        }
        if (done[0] && done[1]) break;
    }
}

extern "C" void kernel_launch(void* const* d_in, const int* in_sizes, int n_in,
                              void* d_out, int out_size, void* d_ws, size_t ws_size,
                              hipStream_t stream)
{
    const float* coord = (const float*)d_in[0];
    const int*   seed  = (const int*)d_in[1];
    float* out = (float*)d_out;
    u64* rec = (u64*)d_ws;

    hipMemsetAsync(d_ws, 0, WS_BYTES, stream);
    fps_kernel<<<dim3(NPAIR * GPB), dim3(TPB), 0, stream>>>(coord, seed, out, rec);
}